// Round 4
// baseline (256.357 us; speedup 1.0000x reference)
//
#include <hip/hip_runtime.h>
#include <math.h>

#define B    64
#define NPG  1024
#define KEIG 32
#define DIN  512
#define DOUT 512
#define NPART 8   // k2 n-chunk partials

__device__ __forceinline__ float rsum32(float v) {
    v += __shfl_xor(v, 1, 32);
    v += __shfl_xor(v, 2, 32);
    v += __shfl_xor(v, 4, 32);
    v += __shfl_xor(v, 8, 32);
    v += __shfl_xor(v, 16, 32);
    return v;
}
__device__ __forceinline__ float rmax32(float v) {
    v = fmaxf(v, __shfl_xor(v, 1, 32));
    v = fmaxf(v, __shfl_xor(v, 2, 32));
    v = fmaxf(v, __shfl_xor(v, 4, 32));
    v = fmaxf(v, __shfl_xor(v, 8, 32));
    v = fmaxf(v, __shfl_xor(v, 16, 32));
    return v;
}

// ---------------------------------------------------------------------------
// Kernel 1: feature-parallel encoder + MHSA + filter head. (unchanged, ~8us)
// ---------------------------------------------------------------------------
__global__ __launch_bounds__(1024) void k1_filters(
    const float* __restrict__ eigenvalues,
    const float* __restrict__ W1,  const float* __restrict__ b1,
    const float* __restrict__ g1,  const float* __restrict__ be1,
    const float* __restrict__ W2,  const float* __restrict__ b2,
    const float* __restrict__ g2,  const float* __restrict__ be2,
    const float* __restrict__ Wqkv,const float* __restrict__ bqkv,
    const float* __restrict__ Wo,  const float* __restrict__ bo,
    const float* __restrict__ Wf1, const float* __restrict__ bf1,
    const float* __restrict__ Wf2, const float* __restrict__ bf2,
    float* __restrict__ filters)
{
    __shared__ float wts[224][33];
    __shared__ float hA[KEIG][33];
    __shared__ float hB[KEIG][33];
    __shared__ float qkv[KEIG][97];
    __shared__ float attn[4 * 1064];

    const int t = threadIdx.x;
    const int k = t >> 5;
    const int j = t & 31;
    const int b = blockIdx.x;

    {
        const int row = t >> 5, i = t & 31;
        wts[row][i]       = W2[t];
        wts[32 + row][i]  = Wqkv[t];
        wts[64 + row][i]  = Wqkv[1024 + t];
        wts[96 + row][i]  = Wqkv[2048 + t];
        wts[128 + row][i] = Wo[t];
        wts[160 + row][i] = Wf1[t];
        wts[192 + row][i] = Wf1[1024 + t];
    }

    const float ev = eigenvalues[b * KEIG + k];
    float h1 = ev * W1[j] + b1[j];
    {
        float m = rsum32(h1) * (1.f / 32.f);
        float d = h1 - m;
        float q = rsum32(d * d);
        float r = rsqrtf(q * (1.f / 32.f) + 1e-5f);
        h1 = fmaxf(d * r * g1[j] + be1[j], 0.f);
    }
    hA[k][j] = h1;
    __syncthreads();

    {
        float a = b2[j];
        #pragma unroll
        for (int i = 0; i < 32; ++i) a += hA[k][i] * wts[j][i];
        float m = rsum32(a) * (1.f / 32.f);
        float d = a - m;
        float q = rsum32(d * d);
        float r = rsqrtf(q * (1.f / 32.f) + 1e-5f);
        hB[k][j] = d * r * g2[j] + be2[j];
    }
    __syncthreads();

    {
        float aq = bqkv[j], ak = bqkv[32 + j], av = bqkv[64 + j];
        #pragma unroll
        for (int i = 0; i < 32; ++i) {
            float hv = hB[k][i];
            aq += hv * wts[32 + j][i];
            ak += hv * wts[64 + j][i];
            av += hv * wts[96 + j][i];
        }
        qkv[k][j]      = aq;
        qkv[k][32 + j] = ak;
        qkv[k][64 + j] = av;
    }
    __syncthreads();

    {
        const float inv = 0.35355339059327373f;
        float sc[4];
        #pragma unroll
        for (int hh = 0; hh < 4; ++hh) {
            float s = 0.f;
            #pragma unroll
            for (int d2 = 0; d2 < 8; ++d2)
                s += qkv[k][hh * 8 + d2] * qkv[j][32 + hh * 8 + d2];
            sc[hh] = s * inv;
        }
        #pragma unroll
        for (int hh = 0; hh < 4; ++hh) {
            float mx  = rmax32(sc[hh]);
            float e   = __expf(sc[hh] - mx);
            float den = rsum32(e);
            attn[hh * 1064 + k * 33 + j] = e / den;
        }
    }
    __syncthreads();

    {
        const int hh = j >> 3;
        float c = 0.f;
        #pragma unroll
        for (int k2 = 0; k2 < 32; ++k2)
            c += attn[hh * 1064 + k * 33 + k2] * qkv[k2][64 + j];
        hA[k][j] = c;
    }
    __syncthreads();

    {
        float o = bo[j];
        #pragma unroll
        for (int i = 0; i < 32; ++i) o += hA[k][i] * wts[128 + j][i];
        hB[k][j] = o;
    }
    __syncthreads();

    {
        float r0 = bf1[j], r1 = bf1[32 + j];
        #pragma unroll
        for (int i = 0; i < 32; ++i) {
            float ov = hB[k][i];
            r0 += ov * wts[160 + j][i];
            r1 += ov * wts[192 + j][i];
        }
        float fp = fmaxf(r0, 0.f) * Wf2[j] + fmaxf(r1, 0.f) * Wf2[32 + j];
        fp = rsum32(fp);
        if (j == 0) filters[b * KEIG + k] = tanhf(fp + bf2[0]);
    }
}

// ---------------------------------------------------------------------------
// Kernel 2 (rewritten): xfp[nc][b][k][d] = sum_{n in 128-row chunk} vg[n,k]*x[n,d]
// grid = B * 8(nc) * 2(dh) = 1024 blocks, 256 threads.
// Thread = (kq = t>>6: 8 k's, ds = t&63: 4 consecutive d's). Per n-iter:
// 1 float4 x load + 2 broadcast b128 vg reads + 32 FMA (prev: 4 b128 / 16 FMA
// -> LDS pipe ~82us/CU was the binding limit).
// ---------------------------------------------------------------------------
__global__ __launch_bounds__(256) void k2_xfreq_partial(
    const float* __restrict__ x, const float* __restrict__ eigvec,
    float* __restrict__ xfp)
{
    __shared__ float vtile[128][32];   // 16 KB
    const int t  = threadIdx.x;
    const int b  = blockIdx.x >> 4;
    const int nc = (blockIdx.x >> 1) & 7;
    const int dh = blockIdx.x & 1;
    const int kq = t >> 6;             // wave index: uniform per wave
    const int ds = t & 63;
    const int d  = dh * 256 + ds * 4;
    const int n0 = nc * 128;

    // stage vg chunk (coalesced)
    const float* vb = eigvec + ((size_t)(b * NPG + n0)) * KEIG;
    #pragma unroll
    for (int e = 0; e < 16; ++e) {
        int idx = t + e * 256;
        ((float*)vtile)[idx] = vb[idx];
    }
    __syncthreads();

    float4 acc[8];
    #pragma unroll
    for (int i = 0; i < 8; ++i) acc[i] = make_float4(0.f, 0.f, 0.f, 0.f);

    const float* xb = x + ((size_t)(b * NPG + n0)) * DIN + d;
    #pragma unroll 4
    for (int n = 0; n < 128; ++n) {
        float4 xv = *(const float4*)(xb + (size_t)n * DIN);
        const float4* vp = (const float4*)&vtile[n][kq * 8];
        float4 v0 = vp[0], v1 = vp[1];
        acc[0].x += v0.x * xv.x; acc[0].y += v0.x * xv.y; acc[0].z += v0.x * xv.z; acc[0].w += v0.x * xv.w;
        acc[1].x += v0.y * xv.x; acc[1].y += v0.y * xv.y; acc[1].z += v0.y * xv.z; acc[1].w += v0.y * xv.w;
        acc[2].x += v0.z * xv.x; acc[2].y += v0.z * xv.y; acc[2].z += v0.z * xv.z; acc[2].w += v0.z * xv.w;
        acc[3].x += v0.w * xv.x; acc[3].y += v0.w * xv.y; acc[3].z += v0.w * xv.z; acc[3].w += v0.w * xv.w;
        acc[4].x += v1.x * xv.x; acc[4].y += v1.x * xv.y; acc[4].z += v1.x * xv.z; acc[4].w += v1.x * xv.w;
        acc[5].x += v1.y * xv.x; acc[5].y += v1.y * xv.y; acc[5].z += v1.y * xv.z; acc[5].w += v1.y * xv.w;
        acc[6].x += v1.z * xv.x; acc[6].y += v1.z * xv.y; acc[6].z += v1.z * xv.z; acc[6].w += v1.z * xv.w;
        acc[7].x += v1.w * xv.x; acc[7].y += v1.w * xv.y; acc[7].z += v1.w * xv.z; acc[7].w += v1.w * xv.w;
    }

    #pragma unroll
    for (int kk = 0; kk < 8; ++kk) {
        int kg = kq * 8 + kk;
        *(float4*)(xfp + (((size_t)nc * B + b) * KEIG + kg) * DIN + d) = acc[kk];
    }
}

// ---------------------------------------------------------------------------
// Kernel 3: stacked GEMM  G[m][o] = sum_d F[m][d] * Wp[o][d],
// F[m][d] = filters[m] * sum_{nc<8} xfp[nc][m][d]  (fused into A staging).
// grid = 32(mtile) x 8(otile) = 256 blocks, 256 threads, 4x4 acc/thread.
// ---------------------------------------------------------------------------
__global__ __launch_bounds__(256) void k3_G(
    const float* __restrict__ xfp, const float* __restrict__ filters,
    const float* __restrict__ Wp, float* __restrict__ G)
{
    __shared__ float a_lds[64][65];
    __shared__ float b_lds[64][65];
    __shared__ float filt_s[64];

    const int t   = threadIdx.x;
    const int mt  = blockIdx.x >> 3;
    const int ot  = blockIdx.x & 7;
    const int m0  = mt * 64;
    const int o0  = ot * 64;
    const int tr  = t >> 4;
    const int tc  = t & 15;
    const int col4 = tc * 4;

    if (t < 64) filt_s[t] = filters[m0 + t];

    float acc[4][4] = {{0.f}};

    for (int d0 = 0; d0 < DIN; d0 += 64) {
        __syncthreads();
        #pragma unroll
        for (int p = 0; p < 4; ++p) {
            int r  = p * 16 + tr;
            int mg = m0 + r;
            const float* base = xfp + ((size_t)(mg >> 5) * 32 + (mg & 31)) * 512 + d0 + col4;
            float4 s = *(const float4*)(base);
            #pragma unroll
            for (int q = 1; q < NPART; ++q) {
                float4 sq = *(const float4*)(base + (size_t)q * 1048576);
                s.x += sq.x; s.y += sq.y; s.z += sq.z; s.w += sq.w;
            }
            float fa = filt_s[r];
            a_lds[r][col4 + 0] = s.x * fa;
            a_lds[r][col4 + 1] = s.y * fa;
            a_lds[r][col4 + 2] = s.z * fa;
            a_lds[r][col4 + 3] = s.w * fa;
        }
        #pragma unroll
        for (int p = 0; p < 4; ++p) {
            int r = p * 16 + tr;
            float4 w = *(const float4*)(Wp + (size_t)(o0 + r) * 512 + d0 + col4);
            b_lds[r][col4 + 0] = w.x;
            b_lds[r][col4 + 1] = w.y;
            b_lds[r][col4 + 2] = w.z;
            b_lds[r][col4 + 3] = w.w;
        }
        __syncthreads();
        #pragma unroll 4
        for (int dd = 0; dd < 64; ++dd) {
            float a0 = a_lds[tr * 4 + 0][dd];
            float a1 = a_lds[tr * 4 + 1][dd];
            float a2 = a_lds[tr * 4 + 2][dd];
            float a3 = a_lds[tr * 4 + 3][dd];
            float b0 = b_lds[tc * 4 + 0][dd];
            float b1 = b_lds[tc * 4 + 1][dd];
            float b2 = b_lds[tc * 4 + 2][dd];
            float b3 = b_lds[tc * 4 + 3][dd];
            acc[0][0] += a0 * b0; acc[0][1] += a0 * b1; acc[0][2] += a0 * b2; acc[0][3] += a0 * b3;
            acc[1][0] += a1 * b0; acc[1][1] += a1 * b1; acc[1][2] += a1 * b2; acc[1][3] += a1 * b3;
            acc[2][0] += a2 * b0; acc[2][1] += a2 * b1; acc[2][2] += a2 * b2; acc[2][3] += a2 * b3;
            acc[3][0] += a3 * b0; acc[3][1] += a3 * b1; acc[3][2] += a3 * b2; acc[3][3] += a3 * b3;
        }
    }
    #pragma unroll
    for (int i = 0; i < 4; ++i) {
        float4 v = make_float4(acc[i][0], acc[i][1], acc[i][2], acc[i][3]);
        *(float4*)(G + (size_t)(m0 + tr * 4 + i) * DOUT + o0 + col4) = v;
    }
}

// ---------------------------------------------------------------------------
// Kernel 4 (rewritten): out[n,o] = LN_o( sum_k vg[n,k]*G[b,k,o] + bp[o] )*gp+bep
// grid = B * 16 = 1024 blocks, 256 threads. Thread owns col pair (2t, 2t+1):
// G held in 64 registers (loaded once, coalesced); vg rows read via uniform
// (scalar-cache) loads. No big LDS -> 4 blocks/CU (prev: 73KB LDS, 2/CU,
// and 2 b32 + 2 b128 LDS reads per 16 FMA saturated the LDS pipe).
// ---------------------------------------------------------------------------
__global__ __launch_bounds__(256) void k4_out(
    const float* __restrict__ eigvec, const float* __restrict__ G,
    const float* __restrict__ bp, const float* __restrict__ gp,
    const float* __restrict__ bep, float* __restrict__ out)
{
    __shared__ float sred[4][8], qred[4][8];

    const int t  = threadIdx.x;
    const int b  = blockIdx.x >> 4;
    const int n0 = (blockIdx.x & 15) * 64;
    const int c0 = 2 * t;

    // G columns for this thread -> registers (coalesced float2 loads)
    float2 g[KEIG];
    #pragma unroll
    for (int k = 0; k < KEIG; ++k)
        g[k] = *(const float2*)(G + ((size_t)b * KEIG + k) * DOUT + c0);

    const float2 bp2 = *(const float2*)(bp + c0);
    const float2 gp2 = *(const float2*)(gp + c0);
    const float2 be2 = *(const float2*)(bep + c0);

    for (int r0 = 0; r0 < 64; r0 += 8) {
        float2 acc[8];
        #pragma unroll
        for (int r = 0; r < 8; ++r) acc[r] = bp2;

        #pragma unroll
        for (int r = 0; r < 8; ++r) {
            // uniform row address -> scalar loads (off the LDS/VMEM-vector path)
            const float4* vr4 = (const float4*)(eigvec +
                ((size_t)(b * NPG + n0 + r0 + r)) * KEIG);
            float4 v0 = vr4[0], v1 = vr4[1], v2 = vr4[2], v3 = vr4[3];
            float4 v4 = vr4[4], v5 = vr4[5], v6 = vr4[6], v7 = vr4[7];
            const float vk[32] = {v0.x,v0.y,v0.z,v0.w, v1.x,v1.y,v1.z,v1.w,
                                  v2.x,v2.y,v2.z,v2.w, v3.x,v3.y,v3.z,v3.w,
                                  v4.x,v4.y,v4.z,v4.w, v5.x,v5.y,v5.z,v5.w,
                                  v6.x,v6.y,v6.z,v6.w, v7.x,v7.y,v7.z,v7.w};
            #pragma unroll
            for (int k = 0; k < KEIG; ++k) {
                acc[r].x += vk[k] * g[k].x;
                acc[r].y += vk[k] * g[k].y;
            }
        }

        // layernorm stats over 512 cols (256 threads x 2 cols)
        float s[8], q[8];
        #pragma unroll
        for (int r = 0; r < 8; ++r) {
            s[r] = acc[r].x + acc[r].y;
            q[r] = acc[r].x * acc[r].x + acc[r].y * acc[r].y;
        }
        #pragma unroll
        for (int off = 1; off < 64; off <<= 1) {
            #pragma unroll
            for (int r = 0; r < 8; ++r) {
                s[r] += __shfl_xor(s[r], off, 64);
                q[r] += __shfl_xor(q[r], off, 64);
            }
        }
        const int wv = t >> 6, ln = t & 63;
        if (ln == 0) {
            #pragma unroll
            for (int r = 0; r < 8; ++r) { sred[wv][r] = s[r]; qred[wv][r] = q[r]; }
        }
        __syncthreads();
        #pragma unroll
        for (int r = 0; r < 8; ++r) {
            float ss = sred[0][r] + sred[1][r] + sred[2][r] + sred[3][r];
            float qq = qred[0][r] + qred[1][r] + qred[2][r] + qred[3][r];
            float m    = ss * (1.f / 512.f);
            float rstd = rsqrtf(qq * (1.f / 512.f) - m * m + 1e-5f);
            size_t row = (size_t)b * NPG + n0 + r0 + r;
            float2 o2;
            o2.x = (acc[r].x - m) * rstd * gp2.x + be2.x;
            o2.y = (acc[r].y - m) * rstd * gp2.y + be2.y;
            *(float2*)(out + row * DOUT + c0) = o2;
        }
        __syncthreads();
    }
}

// ---------------------------------------------------------------------------
extern "C" void kernel_launch(void* const* d_in, const int* in_sizes, int n_in,
                              void* d_out, int out_size, void* d_ws, size_t ws_size,
                              hipStream_t stream) {
    (void)in_sizes; (void)n_in; (void)out_size; (void)ws_size;
    const float* x    = (const float*)d_in[0];
    const float* vg   = (const float*)d_in[1];
    const float* ev   = (const float*)d_in[2];
    const float* W1   = (const float*)d_in[5];
    const float* b1   = (const float*)d_in[6];
    const float* g1   = (const float*)d_in[7];
    const float* be1  = (const float*)d_in[8];
    const float* W2   = (const float*)d_in[9];
    const float* b2   = (const float*)d_in[10];
    const float* g2   = (const float*)d_in[11];
    const float* be2  = (const float*)d_in[12];
    const float* Wqkv = (const float*)d_in[13];
    const float* bqkv = (const float*)d_in[14];
    const float* Wo   = (const float*)d_in[15];
    const float* bo   = (const float*)d_in[16];
    const float* Wf1  = (const float*)d_in[17];
    const float* bf1  = (const float*)d_in[18];
    const float* Wf2  = (const float*)d_in[19];
    const float* bf2  = (const float*)d_in[20];
    const float* Wp   = (const float*)d_in[21];
    const float* bp   = (const float*)d_in[22];
    const float* gp   = (const float*)d_in[23];
    const float* bep  = (const float*)d_in[24];

    float* outf    = (float*)d_out;
    float* ws      = (float*)d_ws;
    float* filters = ws;                         // 2048 floats
    float* G       = ws + 4096;                  // 1,048,576 floats (4 MB)
    float* xfp     = outf;                       // scratch: 8*64*32*512 floats
                                                 // (33.5MB < 134MB), overwritten by k4

    hipLaunchKernelGGL(k1_filters, dim3(B), dim3(1024), 0, stream,
                       ev, W1, b1, g1, be1, W2, b2, g2, be2,
                       Wqkv, bqkv, Wo, bo, Wf1, bf1, Wf2, bf2, filters);
    hipLaunchKernelGGL(k2_xfreq_partial, dim3(B * 16), dim3(256), 0, stream,
                       x, vg, xfp);
    hipLaunchKernelGGL(k3_G, dim3(32 * 8), dim3(256), 0, stream,
                       xfp, filters, Wp, G);
    hipLaunchKernelGGL(k4_out, dim3(B * 16), dim3(256), 0, stream,
                       vg, G, bp, gp, bep, outf);
}

// Round 6
// 131.029 us; speedup vs baseline: 1.9565x; 1.9565x over previous
//
#include <hip/hip_runtime.h>
#include <math.h>

#define B    64
#define NPG  1024
#define KEIG 32
#define DIN  512
#define DOUT 512
#define NPART 8   // k2 n-chunk partials

typedef float f32x4 __attribute__((ext_vector_type(4)));   // native vec for NT stores

__device__ __forceinline__ float rsum32(float v) {
    v += __shfl_xor(v, 1, 32);
    v += __shfl_xor(v, 2, 32);
    v += __shfl_xor(v, 4, 32);
    v += __shfl_xor(v, 8, 32);
    v += __shfl_xor(v, 16, 32);
    return v;
}
__device__ __forceinline__ float rmax32(float v) {
    v = fmaxf(v, __shfl_xor(v, 1, 32));
    v = fmaxf(v, __shfl_xor(v, 2, 32));
    v = fmaxf(v, __shfl_xor(v, 4, 32));
    v = fmaxf(v, __shfl_xor(v, 8, 32));
    v = fmaxf(v, __shfl_xor(v, 16, 32));
    return v;
}
__device__ __forceinline__ float rsum64(float v) {
    v += __shfl_xor(v, 1, 64);
    v += __shfl_xor(v, 2, 64);
    v += __shfl_xor(v, 4, 64);
    v += __shfl_xor(v, 8, 64);
    v += __shfl_xor(v, 16, 64);
    v += __shfl_xor(v, 32, 64);
    return v;
}

// ---------------------------------------------------------------------------
// Kernel 1: feature-parallel encoder + MHSA + filter head. (unchanged, ~8us)
// ---------------------------------------------------------------------------
__global__ __launch_bounds__(1024) void k1_filters(
    const float* __restrict__ eigenvalues,
    const float* __restrict__ W1,  const float* __restrict__ b1,
    const float* __restrict__ g1,  const float* __restrict__ be1,
    const float* __restrict__ W2,  const float* __restrict__ b2,
    const float* __restrict__ g2,  const float* __restrict__ be2,
    const float* __restrict__ Wqkv,const float* __restrict__ bqkv,
    const float* __restrict__ Wo,  const float* __restrict__ bo,
    const float* __restrict__ Wf1, const float* __restrict__ bf1,
    const float* __restrict__ Wf2, const float* __restrict__ bf2,
    float* __restrict__ filters)
{
    __shared__ float wts[224][33];
    __shared__ float hA[KEIG][33];
    __shared__ float hB[KEIG][33];
    __shared__ float qkv[KEIG][97];
    __shared__ float attn[4 * 1064];

    const int t = threadIdx.x;
    const int k = t >> 5;
    const int j = t & 31;
    const int b = blockIdx.x;

    {
        const int row = t >> 5, i = t & 31;
        wts[row][i]       = W2[t];
        wts[32 + row][i]  = Wqkv[t];
        wts[64 + row][i]  = Wqkv[1024 + t];
        wts[96 + row][i]  = Wqkv[2048 + t];
        wts[128 + row][i] = Wo[t];
        wts[160 + row][i] = Wf1[t];
        wts[192 + row][i] = Wf1[1024 + t];
    }

    const float ev = eigenvalues[b * KEIG + k];
    float h1 = ev * W1[j] + b1[j];
    {
        float m = rsum32(h1) * (1.f / 32.f);
        float d = h1 - m;
        float q = rsum32(d * d);
        float r = rsqrtf(q * (1.f / 32.f) + 1e-5f);
        h1 = fmaxf(d * r * g1[j] + be1[j], 0.f);
    }
    hA[k][j] = h1;
    __syncthreads();

    {
        float a = b2[j];
        #pragma unroll
        for (int i = 0; i < 32; ++i) a += hA[k][i] * wts[j][i];
        float m = rsum32(a) * (1.f / 32.f);
        float d = a - m;
        float q = rsum32(d * d);
        float r = rsqrtf(q * (1.f / 32.f) + 1e-5f);
        hB[k][j] = d * r * g2[j] + be2[j];
    }
    __syncthreads();

    {
        float aq = bqkv[j], ak = bqkv[32 + j], av = bqkv[64 + j];
        #pragma unroll
        for (int i = 0; i < 32; ++i) {
            float hv = hB[k][i];
            aq += hv * wts[32 + j][i];
            ak += hv * wts[64 + j][i];
            av += hv * wts[96 + j][i];
        }
        qkv[k][j]      = aq;
        qkv[k][32 + j] = ak;
        qkv[k][64 + j] = av;
    }
    __syncthreads();

    {
        const float inv = 0.35355339059327373f;
        float sc[4];
        #pragma unroll
        for (int hh = 0; hh < 4; ++hh) {
            float s = 0.f;
            #pragma unroll
            for (int d2 = 0; d2 < 8; ++d2)
                s += qkv[k][hh * 8 + d2] * qkv[j][32 + hh * 8 + d2];
            sc[hh] = s * inv;
        }
        #pragma unroll
        for (int hh = 0; hh < 4; ++hh) {
            float mx  = rmax32(sc[hh]);
            float e   = __expf(sc[hh] - mx);
            float den = rsum32(e);
            attn[hh * 1064 + k * 33 + j] = e / den;
        }
    }
    __syncthreads();

    {
        const int hh = j >> 3;
        float c = 0.f;
        #pragma unroll
        for (int k2 = 0; k2 < 32; ++k2)
            c += attn[hh * 1064 + k * 33 + k2] * qkv[k2][64 + j];
        hA[k][j] = c;
    }
    __syncthreads();

    {
        float o = bo[j];
        #pragma unroll
        for (int i = 0; i < 32; ++i) o += hA[k][i] * wts[128 + j][i];
        hB[k][j] = o;
    }
    __syncthreads();

    {
        float r0 = bf1[j], r1 = bf1[32 + j];
        #pragma unroll
        for (int i = 0; i < 32; ++i) {
            float ov = hB[k][i];
            r0 += ov * wts[160 + j][i];
            r1 += ov * wts[192 + j][i];
        }
        float fp = fmaxf(r0, 0.f) * Wf2[j] + fmaxf(r1, 0.f) * Wf2[32 + j];
        fp = rsum32(fp);
        if (j == 0) filters[b * KEIG + k] = tanhf(fp + bf2[0]);
    }
}

// ---------------------------------------------------------------------------
// Kernel 2: xfp[nc][b][k][d] = sum_{n in 128-row chunk} vg[n,k]*x[n,d]
// grid = B * 8(nc) * 2(dh) = 1024 blocks, 256 threads. (unchanged, ~30us)
// ---------------------------------------------------------------------------
__global__ __launch_bounds__(256) void k2_xfreq_partial(
    const float* __restrict__ x, const float* __restrict__ eigvec,
    float* __restrict__ xfp)
{
    __shared__ float vtile[128][32];
    const int t  = threadIdx.x;
    const int b  = blockIdx.x >> 4;
    const int nc = (blockIdx.x >> 1) & 7;
    const int dh = blockIdx.x & 1;
    const int kq = t >> 6;
    const int ds = t & 63;
    const int d  = dh * 256 + ds * 4;
    const int n0 = nc * 128;

    const float* vb = eigvec + ((size_t)(b * NPG + n0)) * KEIG;
    #pragma unroll
    for (int e = 0; e < 16; ++e) {
        int idx = t + e * 256;
        ((float*)vtile)[idx] = vb[idx];
    }
    __syncthreads();

    float4 acc[8];
    #pragma unroll
    for (int i = 0; i < 8; ++i) acc[i] = make_float4(0.f, 0.f, 0.f, 0.f);

    const float* xb = x + ((size_t)(b * NPG + n0)) * DIN + d;
    #pragma unroll 4
    for (int n = 0; n < 128; ++n) {
        float4 xv = *(const float4*)(xb + (size_t)n * DIN);
        const float4* vp = (const float4*)&vtile[n][kq * 8];
        float4 v0 = vp[0], v1 = vp[1];
        acc[0].x += v0.x * xv.x; acc[0].y += v0.x * xv.y; acc[0].z += v0.x * xv.z; acc[0].w += v0.x * xv.w;
        acc[1].x += v0.y * xv.x; acc[1].y += v0.y * xv.y; acc[1].z += v0.y * xv.z; acc[1].w += v0.y * xv.w;
        acc[2].x += v0.z * xv.x; acc[2].y += v0.z * xv.y; acc[2].z += v0.z * xv.z; acc[2].w += v0.z * xv.w;
        acc[3].x += v0.w * xv.x; acc[3].y += v0.w * xv.y; acc[3].z += v0.w * xv.z; acc[3].w += v0.w * xv.w;
        acc[4].x += v1.x * xv.x; acc[4].y += v1.x * xv.y; acc[4].z += v1.x * xv.z; acc[4].w += v1.x * xv.w;
        acc[5].x += v1.y * xv.x; acc[5].y += v1.y * xv.y; acc[5].z += v1.y * xv.z; acc[5].w += v1.y * xv.w;
        acc[6].x += v1.z * xv.x; acc[6].y += v1.z * xv.y; acc[6].z += v1.z * xv.z; acc[6].w += v1.z * xv.w;
        acc[7].x += v1.w * xv.x; acc[7].y += v1.w * xv.y; acc[7].z += v1.w * xv.z; acc[7].w += v1.w * xv.w;
    }

    #pragma unroll
    for (int kk = 0; kk < 8; ++kk) {
        int kg = kq * 8 + kk;
        *(float4*)(xfp + (((size_t)nc * B + b) * KEIG + kg) * DIN + d) = acc[kk];
    }
}

// ---------------------------------------------------------------------------
// Kernel 2b: F[m][d] = filters[m] * sum_nc xfp[nc][m][d].
// Reads the 8 partials exactly ONCE (33.5 MB), writes 4.2 MB.
// grid = 1024 blocks x 256 thr, 2 m-rows per block.
// ---------------------------------------------------------------------------
__global__ __launch_bounds__(256) void k2b_combine(
    const float* __restrict__ xfp, const float* __restrict__ filters,
    float* __restrict__ F)
{
    const int t = threadIdx.x;
    const int m = blockIdx.x * 2 + (t >> 7);
    const int dp = (t & 127) * 4;

    const float* base = xfp + (size_t)m * DIN + dp;
    float4 s = *(const float4*)base;
    #pragma unroll
    for (int q = 1; q < NPART; ++q) {
        float4 sq = *(const float4*)(base + (size_t)q * (B * KEIG * DIN));
        s.x += sq.x; s.y += sq.y; s.z += sq.z; s.w += sq.w;
    }
    const float f = filters[m];
    float4 o = make_float4(s.x * f, s.y * f, s.z * f, s.w * f);
    *(float4*)(F + (size_t)m * DIN + dp) = o;
}

// ---------------------------------------------------------------------------
// Kernel 3: pure GEMM  G[m][o] = sum_d F[m][d] * Wp[o][d].
// M=2048, N=512, K=512. grid = 32(mt) x 8(ot) = 256 blocks, 4x4 acc/thread.
// ---------------------------------------------------------------------------
__global__ __launch_bounds__(256) void k3_G(
    const float* __restrict__ F, const float* __restrict__ Wp,
    float* __restrict__ G)
{
    __shared__ float a_lds[64][65];
    __shared__ float b_lds[64][65];

    const int t   = threadIdx.x;
    const int mt  = blockIdx.x >> 3;
    const int ot  = blockIdx.x & 7;
    const int m0  = mt * 64;
    const int o0  = ot * 64;
    const int tr  = t >> 4;
    const int tc  = t & 15;
    const int col4 = tc * 4;

    float acc[4][4] = {{0.f}};

    for (int d0 = 0; d0 < DIN; d0 += 64) {
        __syncthreads();
        #pragma unroll
        for (int p = 0; p < 4; ++p) {
            int r = p * 16 + tr;
            float4 s = *(const float4*)(F + (size_t)(m0 + r) * DIN + d0 + col4);
            a_lds[r][col4 + 0] = s.x;
            a_lds[r][col4 + 1] = s.y;
            a_lds[r][col4 + 2] = s.z;
            a_lds[r][col4 + 3] = s.w;
        }
        #pragma unroll
        for (int p = 0; p < 4; ++p) {
            int r = p * 16 + tr;
            float4 w = *(const float4*)(Wp + (size_t)(o0 + r) * DIN + d0 + col4);
            b_lds[r][col4 + 0] = w.x;
            b_lds[r][col4 + 1] = w.y;
            b_lds[r][col4 + 2] = w.z;
            b_lds[r][col4 + 3] = w.w;
        }
        __syncthreads();
        #pragma unroll 4
        for (int dd = 0; dd < 64; ++dd) {
            float a0 = a_lds[tr * 4 + 0][dd];
            float a1 = a_lds[tr * 4 + 1][dd];
            float a2 = a_lds[tr * 4 + 2][dd];
            float a3 = a_lds[tr * 4 + 3][dd];
            float b0 = b_lds[tc * 4 + 0][dd];
            float b1 = b_lds[tc * 4 + 1][dd];
            float b2 = b_lds[tc * 4 + 2][dd];
            float b3 = b_lds[tc * 4 + 3][dd];
            acc[0][0] += a0 * b0; acc[0][1] += a0 * b1; acc[0][2] += a0 * b2; acc[0][3] += a0 * b3;
            acc[1][0] += a1 * b0; acc[1][1] += a1 * b1; acc[1][2] += a1 * b2; acc[1][3] += a1 * b3;
            acc[2][0] += a2 * b0; acc[2][1] += a2 * b1; acc[2][2] += a2 * b2; acc[2][3] += a2 * b3;
            acc[3][0] += a3 * b0; acc[3][1] += a3 * b1; acc[3][2] += a3 * b2; acc[3][3] += a3 * b3;
        }
    }
    #pragma unroll
    for (int i = 0; i < 4; ++i) {
        float4 v = make_float4(acc[i][0], acc[i][1], acc[i][2], acc[i][3]);
        *(float4*)(G + (size_t)(m0 + tr * 4 + i) * DOUT + o0 + col4) = v;
    }
}

// ---------------------------------------------------------------------------
// Kernel 4: out[n,:] = LN( vg[n,:] @ G[b] + bp ) * gp + bep
// grid = B*16 = 1024 blocks, 256 thr = 4 independent waves, 16 rows/wave.
// Wave-exclusive rows: LN reduce is a pure wave shfl butterfly -> ZERO
// __syncthreads in the loop. G in LDS read as b128, amortized over 4
// rows/iter; vg transposed in LDS. Nontemporal native-vec float4 stores.
// ---------------------------------------------------------------------------
__global__ __launch_bounds__(256) void k4_out(
    const float* __restrict__ eigvec, const float* __restrict__ G,
    const float* __restrict__ bp, const float* __restrict__ gp,
    const float* __restrict__ bep, float* __restrict__ out)
{
    __shared__ float gsh[KEIG][DOUT];   // 64 KB
    __shared__ float vgt[KEIG][68];     // vg tile transposed [k][row], padded

    const int t  = threadIdx.x;
    const int b  = blockIdx.x >> 4;
    const int n0 = (blockIdx.x & 15) * 64;

    // stage G[b] (64 KB, coalesced float4)
    const float4* G4 = (const float4*)(G + (size_t)b * KEIG * DOUT);
    float4* gsh4 = (float4*)gsh;
    #pragma unroll
    for (int e = 0; e < 16; ++e)
        gsh4[t + e * 256] = G4[t + e * 256];

    // stage vg rows n0..n0+63 transposed
    const float* vb = eigvec + ((size_t)(b * NPG + n0)) * KEIG;
    #pragma unroll
    for (int e = 0; e < 8; ++e) {
        int idx = t + e * 256;
        vgt[idx & 31][idx >> 5] = vb[idx];
    }
    __syncthreads();   // the ONLY barrier

    const int w  = t >> 6;
    const int l  = t & 63;
    const int c0 = 4 * l;     // cols c0..c0+3 and 256+c0..256+c0+3

    const float4 bpA = *(const float4*)(bp + c0);
    const float4 bpB = *(const float4*)(bp + 256 + c0);
    const float4 gpA = *(const float4*)(gp + c0);
    const float4 gpB = *(const float4*)(gp + 256 + c0);
    const float4 beA = *(const float4*)(bep + c0);
    const float4 beB = *(const float4*)(bep + 256 + c0);

    for (int gq = 0; gq < 4; ++gq) {
        const int rbase = w * 16 + gq * 4;     // local rows rbase..rbase+3
        float4 aA[4], aB[4];
        #pragma unroll
        for (int r = 0; r < 4; ++r) { aA[r] = bpA; aB[r] = bpB; }

        #pragma unroll 8
        for (int k = 0; k < KEIG; ++k) {
            const float4 ga = *(const float4*)&gsh[k][c0];
            const float4 gb = *(const float4*)&gsh[k][256 + c0];
            const float4 vv = *(const float4*)&vgt[k][rbase];
            const float vr[4] = {vv.x, vv.y, vv.z, vv.w};
            #pragma unroll
            for (int r = 0; r < 4; ++r) {
                aA[r].x += vr[r] * ga.x; aA[r].y += vr[r] * ga.y;
                aA[r].z += vr[r] * ga.z; aA[r].w += vr[r] * ga.w;
                aB[r].x += vr[r] * gb.x; aB[r].y += vr[r] * gb.y;
                aB[r].z += vr[r] * gb.z; aB[r].w += vr[r] * gb.w;
            }
        }

        #pragma unroll
        for (int r = 0; r < 4; ++r) {
            float s = aA[r].x + aA[r].y + aA[r].z + aA[r].w
                    + aB[r].x + aB[r].y + aB[r].z + aB[r].w;
            float q = aA[r].x * aA[r].x + aA[r].y * aA[r].y
                    + aA[r].z * aA[r].z + aA[r].w * aA[r].w
                    + aB[r].x * aB[r].x + aB[r].y * aB[r].y
                    + aB[r].z * aB[r].z + aB[r].w * aB[r].w;
            s = rsum64(s);
            q = rsum64(q);
            float m    = s * (1.f / 512.f);
            float rstd = rsqrtf(q * (1.f / 512.f) - m * m + 1e-5f);

            f32x4 oA, oB;
            oA.x = (aA[r].x - m) * rstd * gpA.x + beA.x;
            oA.y = (aA[r].y - m) * rstd * gpA.y + beA.y;
            oA.z = (aA[r].z - m) * rstd * gpA.z + beA.z;
            oA.w = (aA[r].w - m) * rstd * gpA.w + beA.w;
            oB.x = (aB[r].x - m) * rstd * gpB.x + beB.x;
            oB.y = (aB[r].y - m) * rstd * gpB.y + beB.y;
            oB.z = (aB[r].z - m) * rstd * gpB.z + beB.z;
            oB.w = (aB[r].w - m) * rstd * gpB.w + beB.w;

            size_t row = (size_t)b * NPG + n0 + rbase + r;
            __builtin_nontemporal_store(oA, (f32x4*)(out + row * DOUT + c0));
            __builtin_nontemporal_store(oB, (f32x4*)(out + row * DOUT + 256 + c0));
        }
    }
}

// ---------------------------------------------------------------------------
extern "C" void kernel_launch(void* const* d_in, const int* in_sizes, int n_in,
                              void* d_out, int out_size, void* d_ws, size_t ws_size,
                              hipStream_t stream) {
    (void)in_sizes; (void)n_in; (void)out_size; (void)ws_size;
    const float* x    = (const float*)d_in[0];
    const float* vg   = (const float*)d_in[1];
    const float* ev   = (const float*)d_in[2];
    const float* W1   = (const float*)d_in[5];
    const float* b1   = (const float*)d_in[6];
    const float* g1   = (const float*)d_in[7];
    const float* be1  = (const float*)d_in[8];
    const float* W2   = (const float*)d_in[9];
    const float* b2   = (const float*)d_in[10];
    const float* g2   = (const float*)d_in[11];
    const float* be2  = (const float*)d_in[12];
    const float* Wqkv = (const float*)d_in[13];
    const float* bqkv = (const float*)d_in[14];
    const float* Wo   = (const float*)d_in[15];
    const float* bo   = (const float*)d_in[16];
    const float* Wf1  = (const float*)d_in[17];
    const float* bf1  = (const float*)d_in[18];
    const float* Wf2  = (const float*)d_in[19];
    const float* bf2  = (const float*)d_in[20];
    const float* Wp   = (const float*)d_in[21];
    const float* bp   = (const float*)d_in[22];
    const float* gp   = (const float*)d_in[23];
    const float* bep  = (const float*)d_in[24];

    float* outf    = (float*)d_out;
    float* ws      = (float*)d_ws;
    float* filters = ws;                         // 2048 floats
    float* G       = ws + 4096;                  // 1,048,576 floats (4 MB)
    float* xfp     = outf;                       // scratch: 33.5 MB at offset 0
    float* F       = outf + 16777216;            // scratch: 4 MB at 64 MB offset
                                                 // (both overwritten by k4)

    hipLaunchKernelGGL(k1_filters, dim3(B), dim3(1024), 0, stream,
                       ev, W1, b1, g1, be1, W2, b2, g2, be2,
                       Wqkv, bqkv, Wo, bo, Wf1, bf1, Wf2, bf2, filters);
    hipLaunchKernelGGL(k2_xfreq_partial, dim3(B * 16), dim3(256), 0, stream,
                       x, vg, xfp);
    hipLaunchKernelGGL(k2b_combine, dim3(1024), dim3(256), 0, stream,
                       xfp, filters, F);
    hipLaunchKernelGGL(k3_G, dim3(32 * 8), dim3(256), 0, stream,
                       F, Wp, G);
    hipLaunchKernelGGL(k4_out, dim3(B * 16), dim3(256), 0, stream,
                       vg, G, bp, gp, bep, outf);
}

// Round 7
// 130.310 us; speedup vs baseline: 1.9673x; 1.0055x over previous
//
#include <hip/hip_runtime.h>
#include <math.h>

#define B    64
#define NPG  1024
#define KEIG 32
#define DIN  512
#define DOUT 512
#define NPART 8   // k2 n-chunk partials

typedef float f32x4 __attribute__((ext_vector_type(4)));   // native vec for NT stores

__device__ __forceinline__ float rsum32(float v) {
    v += __shfl_xor(v, 1, 32);
    v += __shfl_xor(v, 2, 32);
    v += __shfl_xor(v, 4, 32);
    v += __shfl_xor(v, 8, 32);
    v += __shfl_xor(v, 16, 32);
    return v;
}
__device__ __forceinline__ float rmax32(float v) {
    v = fmaxf(v, __shfl_xor(v, 1, 32));
    v = fmaxf(v, __shfl_xor(v, 2, 32));
    v = fmaxf(v, __shfl_xor(v, 4, 32));
    v = fmaxf(v, __shfl_xor(v, 8, 32));
    v = fmaxf(v, __shfl_xor(v, 16, 32));
    return v;
}
__device__ __forceinline__ float rsum64(float v) {
    v += __shfl_xor(v, 1, 64);
    v += __shfl_xor(v, 2, 64);
    v += __shfl_xor(v, 4, 64);
    v += __shfl_xor(v, 8, 64);
    v += __shfl_xor(v, 16, 64);
    v += __shfl_xor(v, 32, 64);
    return v;
}

// ---------------------------------------------------------------------------
// Kernel 1: feature-parallel encoder + MHSA + filter head. (unchanged, ~8us)
// ---------------------------------------------------------------------------
__global__ __launch_bounds__(1024) void k1_filters(
    const float* __restrict__ eigenvalues,
    const float* __restrict__ W1,  const float* __restrict__ b1,
    const float* __restrict__ g1,  const float* __restrict__ be1,
    const float* __restrict__ W2,  const float* __restrict__ b2,
    const float* __restrict__ g2,  const float* __restrict__ be2,
    const float* __restrict__ Wqkv,const float* __restrict__ bqkv,
    const float* __restrict__ Wo,  const float* __restrict__ bo,
    const float* __restrict__ Wf1, const float* __restrict__ bf1,
    const float* __restrict__ Wf2, const float* __restrict__ bf2,
    float* __restrict__ filters)
{
    __shared__ float wts[224][33];
    __shared__ float hA[KEIG][33];
    __shared__ float hB[KEIG][33];
    __shared__ float qkv[KEIG][97];
    __shared__ float attn[4 * 1064];

    const int t = threadIdx.x;
    const int k = t >> 5;
    const int j = t & 31;
    const int b = blockIdx.x;

    {
        const int row = t >> 5, i = t & 31;
        wts[row][i]       = W2[t];
        wts[32 + row][i]  = Wqkv[t];
        wts[64 + row][i]  = Wqkv[1024 + t];
        wts[96 + row][i]  = Wqkv[2048 + t];
        wts[128 + row][i] = Wo[t];
        wts[160 + row][i] = Wf1[t];
        wts[192 + row][i] = Wf1[1024 + t];
    }

    const float ev = eigenvalues[b * KEIG + k];
    float h1 = ev * W1[j] + b1[j];
    {
        float m = rsum32(h1) * (1.f / 32.f);
        float d = h1 - m;
        float q = rsum32(d * d);
        float r = rsqrtf(q * (1.f / 32.f) + 1e-5f);
        h1 = fmaxf(d * r * g1[j] + be1[j], 0.f);
    }
    hA[k][j] = h1;
    __syncthreads();

    {
        float a = b2[j];
        #pragma unroll
        for (int i = 0; i < 32; ++i) a += hA[k][i] * wts[j][i];
        float m = rsum32(a) * (1.f / 32.f);
        float d = a - m;
        float q = rsum32(d * d);
        float r = rsqrtf(q * (1.f / 32.f) + 1e-5f);
        hB[k][j] = d * r * g2[j] + be2[j];
    }
    __syncthreads();

    {
        float aq = bqkv[j], ak = bqkv[32 + j], av = bqkv[64 + j];
        #pragma unroll
        for (int i = 0; i < 32; ++i) {
            float hv = hB[k][i];
            aq += hv * wts[32 + j][i];
            ak += hv * wts[64 + j][i];
            av += hv * wts[96 + j][i];
        }
        qkv[k][j]      = aq;
        qkv[k][32 + j] = ak;
        qkv[k][64 + j] = av;
    }
    __syncthreads();

    {
        const float inv = 0.35355339059327373f;
        float sc[4];
        #pragma unroll
        for (int hh = 0; hh < 4; ++hh) {
            float s = 0.f;
            #pragma unroll
            for (int d2 = 0; d2 < 8; ++d2)
                s += qkv[k][hh * 8 + d2] * qkv[j][32 + hh * 8 + d2];
            sc[hh] = s * inv;
        }
        #pragma unroll
        for (int hh = 0; hh < 4; ++hh) {
            float mx  = rmax32(sc[hh]);
            float e   = __expf(sc[hh] - mx);
            float den = rsum32(e);
            attn[hh * 1064 + k * 33 + j] = e / den;
        }
    }
    __syncthreads();

    {
        const int hh = j >> 3;
        float c = 0.f;
        #pragma unroll
        for (int k2 = 0; k2 < 32; ++k2)
            c += attn[hh * 1064 + k * 33 + k2] * qkv[k2][64 + j];
        hA[k][j] = c;
    }
    __syncthreads();

    {
        float o = bo[j];
        #pragma unroll
        for (int i = 0; i < 32; ++i) o += hA[k][i] * wts[128 + j][i];
        hB[k][j] = o;
    }
    __syncthreads();

    {
        float r0 = bf1[j], r1 = bf1[32 + j];
        #pragma unroll
        for (int i = 0; i < 32; ++i) {
            float ov = hB[k][i];
            r0 += ov * wts[160 + j][i];
            r1 += ov * wts[192 + j][i];
        }
        float fp = fmaxf(r0, 0.f) * Wf2[j] + fmaxf(r1, 0.f) * Wf2[32 + j];
        fp = rsum32(fp);
        if (j == 0) filters[b * KEIG + k] = tanhf(fp + bf2[0]);
    }
}

// ---------------------------------------------------------------------------
// Kernel 2: xfp[nc][b][k][d] = sum_{n in 128-row chunk} vg[n,k]*x[n,d]
// grid = B * 8(nc) * 2(dh) = 1024 blocks, 256 threads. (unchanged, ~30us,
// at its ~28us traffic floor: 134MB x + 34MB xfp + 8MB vg)
// ---------------------------------------------------------------------------
__global__ __launch_bounds__(256) void k2_xfreq_partial(
    const float* __restrict__ x, const float* __restrict__ eigvec,
    float* __restrict__ xfp)
{
    __shared__ float vtile[128][32];
    const int t  = threadIdx.x;
    const int b  = blockIdx.x >> 4;
    const int nc = (blockIdx.x >> 1) & 7;
    const int dh = blockIdx.x & 1;
    const int kq = t >> 6;
    const int ds = t & 63;
    const int d  = dh * 256 + ds * 4;
    const int n0 = nc * 128;

    const float* vb = eigvec + ((size_t)(b * NPG + n0)) * KEIG;
    #pragma unroll
    for (int e = 0; e < 16; ++e) {
        int idx = t + e * 256;
        ((float*)vtile)[idx] = vb[idx];
    }
    __syncthreads();

    float4 acc[8];
    #pragma unroll
    for (int i = 0; i < 8; ++i) acc[i] = make_float4(0.f, 0.f, 0.f, 0.f);

    const float* xb = x + ((size_t)(b * NPG + n0)) * DIN + d;
    #pragma unroll 4
    for (int n = 0; n < 128; ++n) {
        float4 xv = *(const float4*)(xb + (size_t)n * DIN);
        const float4* vp = (const float4*)&vtile[n][kq * 8];
        float4 v0 = vp[0], v1 = vp[1];
        acc[0].x += v0.x * xv.x; acc[0].y += v0.x * xv.y; acc[0].z += v0.x * xv.z; acc[0].w += v0.x * xv.w;
        acc[1].x += v0.y * xv.x; acc[1].y += v0.y * xv.y; acc[1].z += v0.y * xv.z; acc[1].w += v0.y * xv.w;
        acc[2].x += v0.z * xv.x; acc[2].y += v0.z * xv.y; acc[2].z += v0.z * xv.z; acc[2].w += v0.z * xv.w;
        acc[3].x += v0.w * xv.x; acc[3].y += v0.w * xv.y; acc[3].z += v0.w * xv.z; acc[3].w += v0.w * xv.w;
        acc[4].x += v1.x * xv.x; acc[4].y += v1.x * xv.y; acc[4].z += v1.x * xv.z; acc[4].w += v1.x * xv.w;
        acc[5].x += v1.y * xv.x; acc[5].y += v1.y * xv.y; acc[5].z += v1.y * xv.z; acc[5].w += v1.y * xv.w;
        acc[6].x += v1.z * xv.x; acc[6].y += v1.z * xv.y; acc[6].z += v1.z * xv.z; acc[6].w += v1.z * xv.w;
        acc[7].x += v1.w * xv.x; acc[7].y += v1.w * xv.y; acc[7].z += v1.w * xv.z; acc[7].w += v1.w * xv.w;
    }

    #pragma unroll
    for (int kk = 0; kk < 8; ++kk) {
        int kg = kq * 8 + kk;
        *(float4*)(xfp + (((size_t)nc * B + b) * KEIG + kg) * DIN + d) = acc[kk];
    }
}

// ---------------------------------------------------------------------------
// Kernel 2b: F[m][d] = filters[m] * sum_nc xfp[nc][m][d].
// Reads the 8 partials exactly ONCE (33.5 MB), writes 4.2 MB. (~7us)
// ---------------------------------------------------------------------------
__global__ __launch_bounds__(256) void k2b_combine(
    const float* __restrict__ xfp, const float* __restrict__ filters,
    float* __restrict__ F)
{
    const int t = threadIdx.x;
    const int m = blockIdx.x * 2 + (t >> 7);
    const int dp = (t & 127) * 4;

    const float* base = xfp + (size_t)m * DIN + dp;
    float4 s = *(const float4*)base;
    #pragma unroll
    for (int q = 1; q < NPART; ++q) {
        float4 sq = *(const float4*)(base + (size_t)q * (B * KEIG * DIN));
        s.x += sq.x; s.y += sq.y; s.z += sq.z; s.w += sq.w;
    }
    const float f = filters[m];
    float4 o = make_float4(s.x * f, s.y * f, s.z * f, s.w * f);
    *(float4*)(F + (size_t)m * DIN + dp) = o;
}

// ---------------------------------------------------------------------------
// Kernel 3: pure GEMM  G[m][o] = sum_d F[m][d] * Wp[o][d].
// M=2048, N=512, K=512. grid = 32(mt) x 8(ot) = 256 blocks, 4x4 acc/thread.
// ---------------------------------------------------------------------------
__global__ __launch_bounds__(256) void k3_G(
    const float* __restrict__ F, const float* __restrict__ Wp,
    float* __restrict__ G)
{
    __shared__ float a_lds[64][65];
    __shared__ float b_lds[64][65];

    const int t   = threadIdx.x;
    const int mt  = blockIdx.x >> 3;
    const int ot  = blockIdx.x & 7;
    const int m0  = mt * 64;
    const int o0  = ot * 64;
    const int tr  = t >> 4;
    const int tc  = t & 15;
    const int col4 = tc * 4;

    float acc[4][4] = {{0.f}};

    for (int d0 = 0; d0 < DIN; d0 += 64) {
        __syncthreads();
        #pragma unroll
        for (int p = 0; p < 4; ++p) {
            int r = p * 16 + tr;
            float4 s = *(const float4*)(F + (size_t)(m0 + r) * DIN + d0 + col4);
            a_lds[r][col4 + 0] = s.x;
            a_lds[r][col4 + 1] = s.y;
            a_lds[r][col4 + 2] = s.z;
            a_lds[r][col4 + 3] = s.w;
        }
        #pragma unroll
        for (int p = 0; p < 4; ++p) {
            int r = p * 16 + tr;
            float4 w = *(const float4*)(Wp + (size_t)(o0 + r) * DIN + d0 + col4);
            b_lds[r][col4 + 0] = w.x;
            b_lds[r][col4 + 1] = w.y;
            b_lds[r][col4 + 2] = w.z;
            b_lds[r][col4 + 3] = w.w;
        }
        __syncthreads();
        #pragma unroll 4
        for (int dd = 0; dd < 64; ++dd) {
            float a0 = a_lds[tr * 4 + 0][dd];
            float a1 = a_lds[tr * 4 + 1][dd];
            float a2 = a_lds[tr * 4 + 2][dd];
            float a3 = a_lds[tr * 4 + 3][dd];
            float b0 = b_lds[tc * 4 + 0][dd];
            float b1 = b_lds[tc * 4 + 1][dd];
            float b2 = b_lds[tc * 4 + 2][dd];
            float b3 = b_lds[tc * 4 + 3][dd];
            acc[0][0] += a0 * b0; acc[0][1] += a0 * b1; acc[0][2] += a0 * b2; acc[0][3] += a0 * b3;
            acc[1][0] += a1 * b0; acc[1][1] += a1 * b1; acc[1][2] += a1 * b2; acc[1][3] += a1 * b3;
            acc[2][0] += a2 * b0; acc[2][1] += a2 * b1; acc[2][2] += a2 * b2; acc[2][3] += a2 * b3;
            acc[3][0] += a3 * b0; acc[3][1] += a3 * b1; acc[3][2] += a3 * b2; acc[3][3] += a3 * b3;
        }
    }
    #pragma unroll
    for (int i = 0; i < 4; ++i) {
        float4 v = make_float4(acc[i][0], acc[i][1], acc[i][2], acc[i][3]);
        *(float4*)(G + (size_t)(m0 + tr * 4 + i) * DOUT + o0 + col4) = v;
    }
}

// ---------------------------------------------------------------------------
// Kernel 4 (v3): out[n,:] = LN( vg[n,:] @ G[b] + bp ) * gp + bep
// grid = B*16 = 1024 blocks, 256 thr = 4 waves; wave owns 16 FULL rows,
// processed in ONE pass: per k-iter 2 b128 G-reads + 4 broadcast b128
// vg-reads feed 128 FMAs (prev: 4-row passes, 12 b128 per 128 FMA ->
// LDS pipe ~31us/CU). acc = 128 VGPR; launch_bounds(256,2) permits it
// (LDS 74KB caps at 2 blocks/CU = 2 waves/SIMD regardless).
// ---------------------------------------------------------------------------
__global__ __launch_bounds__(256, 2) void k4_out(
    const float* __restrict__ eigvec, const float* __restrict__ G,
    const float* __restrict__ bp, const float* __restrict__ gp,
    const float* __restrict__ bep, float* __restrict__ out)
{
    __shared__ float gsh[KEIG][DOUT];   // 64 KB
    __shared__ float vgt[KEIG][68];     // vg tile transposed [k][row], padded

    const int t  = threadIdx.x;
    const int b  = blockIdx.x >> 4;
    const int n0 = (blockIdx.x & 15) * 64;

    // stage G[b] (64 KB, coalesced float4)
    const float4* G4 = (const float4*)(G + (size_t)b * KEIG * DOUT);
    float4* gsh4 = (float4*)gsh;
    #pragma unroll
    for (int e = 0; e < 16; ++e)
        gsh4[t + e * 256] = G4[t + e * 256];

    // stage vg rows n0..n0+63 transposed
    const float* vb = eigvec + ((size_t)(b * NPG + n0)) * KEIG;
    #pragma unroll
    for (int e = 0; e < 8; ++e) {
        int idx = t + e * 256;
        vgt[idx & 31][idx >> 5] = vb[idx];
    }
    __syncthreads();   // the ONLY barrier

    const int w     = t >> 6;
    const int l     = t & 63;
    const int c0    = 4 * l;       // cols c0..c0+3 and 256+c0..+3
    const int rbase = w * 16;      // this wave's 16 local rows

    const float4 bpA = *(const float4*)(bp + c0);
    const float4 bpB = *(const float4*)(bp + 256 + c0);
    const float4 gpA = *(const float4*)(gp + c0);
    const float4 gpB = *(const float4*)(gp + 256 + c0);
    const float4 beA = *(const float4*)(bep + c0);
    const float4 beB = *(const float4*)(bep + 256 + c0);

    float4 aA[16], aB[16];
    #pragma unroll
    for (int r = 0; r < 16; ++r) { aA[r] = bpA; aB[r] = bpB; }

    for (int k = 0; k < KEIG; ++k) {
        const float4 ga = *(const float4*)&gsh[k][c0];
        const float4 gb = *(const float4*)&gsh[k][256 + c0];
        const float4 v0 = *(const float4*)&vgt[k][rbase];
        const float4 v1 = *(const float4*)&vgt[k][rbase + 4];
        const float4 v2 = *(const float4*)&vgt[k][rbase + 8];
        const float4 v3 = *(const float4*)&vgt[k][rbase + 12];
        const float vr[16] = {v0.x,v0.y,v0.z,v0.w, v1.x,v1.y,v1.z,v1.w,
                              v2.x,v2.y,v2.z,v2.w, v3.x,v3.y,v3.z,v3.w};
        #pragma unroll
        for (int r = 0; r < 16; ++r) {
            aA[r].x += vr[r] * ga.x; aA[r].y += vr[r] * ga.y;
            aA[r].z += vr[r] * ga.z; aA[r].w += vr[r] * ga.w;
            aB[r].x += vr[r] * gb.x; aB[r].y += vr[r] * gb.y;
            aB[r].z += vr[r] * gb.z; aB[r].w += vr[r] * gb.w;
        }
    }

    #pragma unroll
    for (int r = 0; r < 16; ++r) {
        float s = aA[r].x + aA[r].y + aA[r].z + aA[r].w
                + aB[r].x + aB[r].y + aB[r].z + aB[r].w;
        float q = aA[r].x * aA[r].x + aA[r].y * aA[r].y
                + aA[r].z * aA[r].z + aA[r].w * aA[r].w
                + aB[r].x * aB[r].x + aB[r].y * aB[r].y
                + aB[r].z * aB[r].z + aB[r].w * aB[r].w;
        s = rsum64(s);
        q = rsum64(q);
        float m    = s * (1.f / 512.f);
        float rstd = rsqrtf(q * (1.f / 512.f) - m * m + 1e-5f);

        f32x4 oA, oB;
        oA.x = (aA[r].x - m) * rstd * gpA.x + beA.x;
        oA.y = (aA[r].y - m) * rstd * gpA.y + beA.y;
        oA.z = (aA[r].z - m) * rstd * gpA.z + beA.z;
        oA.w = (aA[r].w - m) * rstd * gpA.w + beA.w;
        oB.x = (aB[r].x - m) * rstd * gpB.x + beB.x;
        oB.y = (aB[r].y - m) * rstd * gpB.y + beB.y;
        oB.z = (aB[r].z - m) * rstd * gpB.z + beB.z;
        oB.w = (aB[r].w - m) * rstd * gpB.w + beB.w;

        size_t row = (size_t)b * NPG + n0 + rbase + r;
        __builtin_nontemporal_store(oA, (f32x4*)(out + row * DOUT + c0));
        __builtin_nontemporal_store(oB, (f32x4*)(out + row * DOUT + 256 + c0));
    }
}

// ---------------------------------------------------------------------------
extern "C" void kernel_launch(void* const* d_in, const int* in_sizes, int n_in,
                              void* d_out, int out_size, void* d_ws, size_t ws_size,
                              hipStream_t stream) {
    (void)in_sizes; (void)n_in; (void)out_size; (void)ws_size;
    const float* x    = (const float*)d_in[0];
    const float* vg   = (const float*)d_in[1];
    const float* ev   = (const float*)d_in[2];
    const float* W1   = (const float*)d_in[5];
    const float* b1   = (const float*)d_in[6];
    const float* g1   = (const float*)d_in[7];
    const float* be1  = (const float*)d_in[8];
    const float* W2   = (const float*)d_in[9];
    const float* b2   = (const float*)d_in[10];
    const float* g2   = (const float*)d_in[11];
    const float* be2  = (const float*)d_in[12];
    const float* Wqkv = (const float*)d_in[13];
    const float* bqkv = (const float*)d_in[14];
    const float* Wo   = (const float*)d_in[15];
    const float* bo   = (const float*)d_in[16];
    const float* Wf1  = (const float*)d_in[17];
    const float* bf1  = (const float*)d_in[18];
    const float* Wf2  = (const float*)d_in[19];
    const float* bf2  = (const float*)d_in[20];
    const float* Wp   = (const float*)d_in[21];
    const float* bp   = (const float*)d_in[22];
    const float* gp   = (const float*)d_in[23];
    const float* bep  = (const float*)d_in[24];

    float* outf    = (float*)d_out;
    float* ws      = (float*)d_ws;
    float* filters = ws;                         // 2048 floats
    float* G       = ws + 4096;                  // 1,048,576 floats (4 MB)
    float* xfp     = outf;                       // scratch: 33.5 MB at offset 0
    float* F       = outf + 16777216;            // scratch: 4 MB at 64 MB offset
                                                 // (both overwritten by k4)

    hipLaunchKernelGGL(k1_filters, dim3(B), dim3(1024), 0, stream,
                       ev, W1, b1, g1, be1, W2, b2, g2, be2,
                       Wqkv, bqkv, Wo, bo, Wf1, bf1, Wf2, bf2, filters);
    hipLaunchKernelGGL(k2_xfreq_partial, dim3(B * 16), dim3(256), 0, stream,
                       x, vg, xfp);
    hipLaunchKernelGGL(k2b_combine, dim3(1024), dim3(256), 0, stream,
                       xfp, filters, F);
    hipLaunchKernelGGL(k3_G, dim3(32 * 8), dim3(256), 0, stream,
                       F, Wp, G);
    hipLaunchKernelGGL(k4_out, dim3(B * 16), dim3(256), 0, stream,
                       vg, G, bp, gp, bep, outf);
}